// Round 4
// baseline (148.906 us; speedup 1.0000x reference)
//
#include <hip/hip_runtime.h>
#include <cfloat>

typedef __attribute__((ext_vector_type(8))) short short8;
typedef __attribute__((ext_vector_type(4))) float f32x4;

#define NE 1024
#define EDIM 256
#define HW 1024
#define BSTRIDE (EDIM * HW)        // 262144
#define TOTAL 8388608

// workspace layout (bytes)
#define EMBS_OFF  0                        // bf16 B, MFMA-frag-swizzled: 512 KB
#define ENORM_OFF (512 * 1024)             // float[1024]
#define HIST_OFF  (ENORM_OFF + 4096)       // int[1024]
#define LOSS_OFF  (HIST_OFF + 4096)        // float accumulator

// round-to-nearest-even fp32 -> bf16 bits (inputs are finite)
__device__ __forceinline__ unsigned short f2bf(float x) {
    unsigned u = __builtin_bit_cast(unsigned, x);
    return (unsigned short)((u + 0x7fffu + ((u >> 16) & 1u)) >> 16);
}

// ---------------------------------------------------------------------------
// P: emb fp32 [1024][256] -> embS bf16 in MFMA-B-fragment order + enorm.
// embS short8 slot layout: [(code>>4)*8 + ks][lane], lane=(q<<4)|lm holds
// code = tile*16+lm, k = ks*32 + q*8 .. +8. A wave's B-frag load is then a
// single coalesced 1 KB dwordx4. 32 blocks x 256 thr; thread = (row, ks).
// Also zeroes hist/lossAcc (harness poisons ws every launch).
// ---------------------------------------------------------------------------
__global__ void prep_emb(const float* __restrict__ emb,
                         unsigned short* __restrict__ embS,
                         float* __restrict__ enorm,
                         int* __restrict__ hist, float* __restrict__ lossAcc) {
    int gid = blockIdx.x * 256 + threadIdx.x;   // 0..8191
    int row = gid >> 3, ks = gid & 7;
    const float4* e4 = (const float4*)(emb + (size_t)row * EDIM + ks * 32);
    float s = 0.f;
    short8 v[4];
#pragma unroll
    for (int q = 0; q < 4; ++q) {
        float4 a = e4[2 * q], b = e4[2 * q + 1];
        s += a.x * a.x + a.y * a.y + a.z * a.z + a.w * a.w
           + b.x * b.x + b.y * b.y + b.z * b.z + b.w * b.w;
        v[q][0] = (short)f2bf(a.x); v[q][1] = (short)f2bf(a.y);
        v[q][2] = (short)f2bf(a.z); v[q][3] = (short)f2bf(a.w);
        v[q][4] = (short)f2bf(b.x); v[q][5] = (short)f2bf(b.y);
        v[q][6] = (short)f2bf(b.z); v[q][7] = (short)f2bf(b.w);
    }
    short8* o = (short8*)embS;
    int base = ((row >> 4) * 8 + ks) * 64 + (row & 15);
#pragma unroll
    for (int q = 0; q < 4; ++q) o[base + q * 16] = v[q];
    s += __shfl_xor(s, 1, 64);
    s += __shfl_xor(s, 2, 64);
    s += __shfl_xor(s, 4, 64);
    if (ks == 0) enorm[row] = s;
    if (gid < NE) hist[gid] = 0;
    if (gid == NE) lossAcc[0] = 0.f;
}

// ---------------------------------------------------------------------------
// F: fused argmin + gather + loss + hist. Block = 64 positions, grid 512.
// Each wave holds ALL 64 positions as A-frags (A[4][8] in regs) and owns a
// disjoint 256-code quarter; B-frags stream from L2 as coalesced 1 KB loads
// (pre-swizzled). Zero barriers in the main loop.
// Epilogue: stage selected fp32 emb rows into LDS, coalesced z_q + loss.
// ---------------------------------------------------------------------------
__global__ __launch_bounds__(256, 2) void fused_kernel(
        const float* __restrict__ z, const float* __restrict__ emb,
        const short8* __restrict__ embS, const float* __restrict__ enormG,
        float* __restrict__ zq, int* __restrict__ hist,
        float* __restrict__ lossAcc) {
    // union: As 64x264 bf16 (33.8 KB) / Es 256 ch x 17 float4 slots (69.6 KB)
    __shared__ __align__(16) char smem[256 * 17 * 16];
    __shared__ float Ens[NE];
    __shared__ float rv[4][64];
    __shared__ int   ri[4][64];
    __shared__ int   idxm[64];

    unsigned short* As = (unsigned short*)smem;
    float4*         Es = (float4*)smem;
    float*         Esf = (float*)smem;

    int t = threadIdx.x;
    int m0 = blockIdx.x * 64;
    int b = m0 >> 10, pb = m0 & 1023;
    const float* zb  = z  + (size_t)b * BSTRIDE + pb;
    float*       zqb = zq + (size_t)b * BSTRIDE + pb;

    for (int j = t; j < NE; j += 256) Ens[j] = enormG[j];

    {   // stage A: 64 positions x 256 channels, bf16, [p][c], short8 stores
        int p = t & 63, cg = t >> 6;
        const float* zp = zb + p;
        for (int c8 = 0; c8 < 8; ++c8) {
            short8 v;
#pragma unroll
            for (int j = 0; j < 8; ++j)
                v[j] = (short)f2bf(zp[(size_t)(cg * 64 + c8 * 8 + j) * HW]);
            *(short8*)&As[p * 264 + cg * 64 + c8 * 8] = v;
        }
    }
    __syncthreads();

    int w = t >> 6, l = t & 63, lm = l & 15, q = l >> 4;

    short8 A[4][8];
#pragma unroll
    for (int mf = 0; mf < 4; ++mf)
#pragma unroll
        for (int ks = 0; ks < 8; ++ks)
            A[mf][ks] = *(const short8*)&As[(mf * 16 + lm) * 264 + ks * 32 + q * 8];

    float bd[16]; int bi[16];
#pragma unroll
    for (int i = 0; i < 16; ++i) { bd[i] = FLT_MAX; bi[i] = 0x7fffffff; }

    // wave's code quarter = 16 n-tiles of 16 codes; frag stream is coalesced
    const short8* eS = embS + (size_t)(w * 16) * 8 * 64 + l;
    for (int nt = 0; nt < 16; ++nt) {
        const short8* ep = eS + nt * 8 * 64;
        f32x4 acc[4];
#pragma unroll
        for (int mf = 0; mf < 4; ++mf) acc[mf] = (f32x4){0.f, 0.f, 0.f, 0.f};
#pragma unroll
        for (int ks = 0; ks < 8; ++ks) {
            short8 Bv = ep[ks * 64];
            acc[0] = __builtin_amdgcn_mfma_f32_16x16x32_bf16(A[0][ks], Bv, acc[0], 0, 0, 0);
            acc[1] = __builtin_amdgcn_mfma_f32_16x16x32_bf16(A[1][ks], Bv, acc[1], 0, 0, 0);
            acc[2] = __builtin_amdgcn_mfma_f32_16x16x32_bf16(A[2][ks], Bv, acc[2], 0, 0, 0);
            acc[3] = __builtin_amdgcn_mfma_f32_16x16x32_bf16(A[3][ks], Bv, acc[3], 0, 0, 0);
        }
        int code = w * 256 + nt * 16 + lm;
        float en = Ens[code];
#pragma unroll
        for (int mf = 0; mf < 4; ++mf)
#pragma unroll
            for (int r = 0; r < 4; ++r) {
                float d = en - 2.f * acc[mf][r];
                int s = mf * 4 + r;
                if (d < bd[s]) { bd[s] = d; bi[s] = code; }
            }
    }

    // reduce across the 16 code-columns (lanes sharing q)
#pragma unroll
    for (int off = 1; off < 16; off <<= 1) {
#pragma unroll
        for (int i = 0; i < 16; ++i) {
            float od = __shfl_xor(bd[i], off, 64);
            int   oi = __shfl_xor(bi[i], off, 64);
            if (od < bd[i] || (od == bd[i] && oi < bi[i])) { bd[i] = od; bi[i] = oi; }
        }
    }
    if (lm == 0) {
#pragma unroll
        for (int mf = 0; mf < 4; ++mf)
#pragma unroll
            for (int r = 0; r < 4; ++r) {
                int p = mf * 16 + q * 4 + r;      // D row = q*4+r
                rv[w][p] = bd[mf * 4 + r];
                ri[w][p] = bi[mf * 4 + r];
            }
    }
    __syncthreads();
    if (t < 64) {   // merge the 4 waves' disjoint ascending code ranges
        float bv = rv[0][t]; int bidx = ri[0][t];
#pragma unroll
        for (int ww = 1; ww < 4; ++ww) {
            float v = rv[ww][t]; int ii = ri[ww][t];
            if (v < bv || (v == bv && ii < bidx)) { bv = v; bidx = ii; }
        }
        idxm[t] = bidx;
        atomicAdd(&hist[bidx], 1);
    }
    __syncthreads();   // idxm ready; As no longer needed -> Es overlay

    {   // stage selected fp32 emb rows: position r, quarter qo
        int r = t >> 2, qo = t & 3;
        int kr = idxm[r];
        const float4* er = (const float4*)(emb + (size_t)kr * EDIM);
        int base = (r >> 2) * 4 + (r & 3);     // dword offset within c-row
#pragma unroll
        for (int u = 0; u < 16; ++u) {
            float4 v = er[qo * 16 + u];
            int c = (qo * 16 + u) * 4;
            Esf[(c + 0) * 68 + base] = v.x;
            Esf[(c + 1) * 68 + base] = v.y;
            Esf[(c + 2) * 68 + base] = v.z;
            Esf[(c + 3) * 68 + base] = v.w;
        }
    }
    __syncthreads();

    {   // z_q write + loss: thread = (p-quad, 16 channels)
        int pq = t & 15, cg2 = t >> 4;
        float ls = 0.f;
#pragma unroll 4
        for (int cc = 0; cc < 16; ++cc) {
            int c = cg2 * 16 + cc;
            float4 zv = *(const float4*)&zb[(size_t)c * HW + pq * 4];
            float4 ev = Es[c * 17 + pq];
            *(float4*)&zqb[(size_t)c * HW + pq * 4] = ev;
            float dx = ev.x - zv.x, dy = ev.y - zv.y;
            float dz = ev.z - zv.z, dw = ev.w - zv.w;
            ls += dx * dx + dy * dy + dz * dz + dw * dw;
        }
#pragma unroll
        for (int off = 32; off; off >>= 1) ls += __shfl_down(ls, off, 64);
        if ((t & 63) == 0) atomicAdd(lossAcc, ls);
    }
}

// ---------------------------------------------------------------------------
// Z: finalize loss + perplexity into d_out tail.
// ---------------------------------------------------------------------------
__global__ void finalize_kernel(const int* __restrict__ hist,
                                const float* __restrict__ lossAcc,
                                float* __restrict__ out) {
    __shared__ float wsum[4];
    int t = threadIdx.x;
    float s = 0.f;
    for (int j = t; j < NE; j += 256) {
        float p = (float)hist[j] * (1.0f / 32768.0f);
        s += p * logf(p + 1e-10f);
    }
#pragma unroll
    for (int off = 32; off; off >>= 1) s += __shfl_down(s, off, 64);
    if ((t & 63) == 0) wsum[t >> 6] = s;
    __syncthreads();
    if (t == 0) {
        float S = wsum[0] + wsum[1] + wsum[2] + wsum[3];
        out[TOTAL]     = 1.25f * lossAcc[0] / (float)TOTAL;
        out[TOTAL + 1] = expf(-S);
    }
}

extern "C" void kernel_launch(void* const* d_in, const int* in_sizes, int n_in,
                              void* d_out, int out_size, void* d_ws, size_t ws_size,
                              hipStream_t stream) {
    (void)in_sizes; (void)n_in; (void)out_size; (void)ws_size;
    const float* z   = (const float*)d_in[0];
    const float* emb = (const float*)d_in[1];
    float* out = (float*)d_out;
    char* ws = (char*)d_ws;
    unsigned short* embS = (unsigned short*)(ws + EMBS_OFF);
    float* enorm   = (float*)(ws + ENORM_OFF);
    int*   hist    = (int*)(ws + HIST_OFF);
    float* lossAcc = (float*)(ws + LOSS_OFF);

    prep_emb<<<32, 256, 0, stream>>>(emb, embS, enorm, hist, lossAcc);
    fused_kernel<<<512, 256, 0, stream>>>(z, emb, (const short8*)embS, enorm,
                                          out, hist, lossAcc);
    finalize_kernel<<<1, 256, 0, stream>>>(hist, lossAcc, out);
}